// Round 10
// baseline (511.045 us; speedup 1.0000x reference)
//
#include <hip/hip_runtime.h>

#define HOUT 15
#define WOUT 15
// input  (32, 32, 32, 32, 16)  fp32
// ncv    (32, 32, 15, 15, 16)  fp32
// w      (3, 3, 32, 4, 4, 32)  fp32
// out    (32, 32, 15, 15, 16)  fp32

typedef float v2 __attribute__((ext_vector_type(2)));

// DPP butterfly add step (ctrl must be a literal). Compiler-generated DPP
// gets hazard NOPs inserted automatically — verified correct rounds 1-4, 8, 9.
#define DPP_ADDF(x, ctrl) \
    ((x) + __builtin_bit_cast(float, __builtin_amdgcn_update_dpp( \
        0, __builtin_bit_cast(int, (x)), (ctrl), 0xF, 0xF, true)))

// ---------------- pass 0: repack w for the (m, d-half) lane mapping --------
// w[kl][n][x][d][m] -> w3[n][kl][xq][l64][e]  (147456 floats = 576 KB)
// lane l64 = m + 32*half owns d in {2*half, 2*half+1}. Element e of quad xq:
//   x = 2*xq + (e>>1), d = 2*half + (e&1)
__global__ __launch_bounds__(256) void prep_w(const float* __restrict__ wt,
                                              float* __restrict__ w3)
{
    const int t   = blockIdx.x * 256 + threadIdx.x;   // 0..147455
    const int e   = t & 3;
    const int l64 = (t >> 2) & 63;
    const int xq  = (t >> 8) & 1;
    const int r   = t >> 9;          // n*9 + kl
    const int kl  = r % 9;
    const int n   = r / 9;
    const int mm  = l64 & 31;
    const int hf  = l64 >> 5;
    const int x   = 2 * xq + (e >> 1);
    const int d   = 2 * hf + (e & 1);
    w3[t] = wt[((kl * 32 + n) * 16 + x * 4 + d) * 32 + mm];
}

// ---------------- fused kernel: one wave per output position ---------------
// lane = m + 32*half; half owns d-pair {2h, 2h+1}.
// KEY CHANGE vs round 9: av loads moved from SMEM (s_load) to VMEM.
// Rationale: SMEM shares lgkmcnt with ds_bpermute/ds_swizzle, and SMEM
// returns out-of-order, so every softmax cross-lane wait was
// s_waitcnt lgkmcnt(0) — draining ALL in-flight av prefetch (why R8's
// prefetch and R9's dual streams under-delivered). The input base pointer
// is laundered through an empty asm so the compiler cannot prove it
// uniform -> keeps it in VGPRs -> global_load_dwordx4 (vmcnt), which
// survives the cross-lane waits. Arithmetic identical to round 9.
// NOTE: no min-waves clause (round 2: forced cap -> spill -> 3.4x regression).
__global__ __launch_bounds__(256) void caps_all(
    const float* __restrict__ input,
    const float* __restrict__ ncv,
    const float* __restrict__ w3,
    const float* __restrict__ gamma,
    const float* __restrict__ beta,
    float* __restrict__ out)
{
    const int tid  = threadIdx.x;
    const int l64  = tid & 63;
    const int m    = l64 & 31;
    const int half = l64 >> 5;

    const int posu = __builtin_amdgcn_readfirstlane(blockIdx.x * 4 + (tid >> 6));
    const int b  = posu / (HOUT * WOUT);
    const int hw = posu % (HOUT * WOUT);
    const int h  = hw / WOUT;
    const int wo = hw % WOUT;

    // input[b][n][h][w][16]: strides 524288 / 16384 / 512 / 16
    const float* ipb = input + (size_t)b * 524288 + (h * 2) * 512 + (wo * 2) * 16;
    // launder: force the (wave-uniform) base into VGPRs so av loads are VMEM
    {
        unsigned long long ipv = (unsigned long long)ipb;
        asm("" : "+v"(ipv));
        ipb = (const float*)ipv;
    }

    // cv = ncv[b][m][h][wo][a*4 + 2*half + {0,1}], pre-scaled by 0.25*log2e
    const float* cvp = ncv + (((size_t)b * 32 + m) * (HOUT * WOUT) + hw) * 16 + 2 * half;
    const float SC = 0.36067376022224085f;   // 0.25 * log2(e)
    v2 sc2 = {SC, SC};
    v2 cv0 = *(const v2*)(cvp +  0) * sc2;
    v2 cv1 = *(const v2*)(cvp +  4) * sc2;
    v2 cv2 = *(const v2*)(cvp +  8) * sc2;
    v2 cv3 = *(const v2*)(cvp + 12) * sc2;

    v2 acA0 = {0.f,0.f}, acA1 = {0.f,0.f}, acA2 = {0.f,0.f}, acA3 = {0.f,0.f};
    v2 acB0 = {0.f,0.f}, acB1 = {0.f,0.f}, acB2 = {0.f,0.f}, acB3 = {0.f,0.f};

    // u[a] = sum_x av[a,x] * w[x, dpair, m] for one site
    auto site_u = [&](const float4& A0, const float4& A1,
                      const float4& A2, const float4& A3,
                      const float4& Q0, const float4& Q1,
                      v2& U0, v2& U1, v2& U2, v2& U3) {
        const v2 W0 = {Q0.x, Q0.y}, W1 = {Q0.z, Q0.w};
        const v2 W2 = {Q1.x, Q1.y}, W3 = {Q1.z, Q1.w};
        U0 = (v2){A0.x, A0.x} * W0;
        U0 = __builtin_elementwise_fma((v2){A0.y, A0.y}, W1, U0);
        U0 = __builtin_elementwise_fma((v2){A0.z, A0.z}, W2, U0);
        U0 = __builtin_elementwise_fma((v2){A0.w, A0.w}, W3, U0);
        U1 = (v2){A1.x, A1.x} * W0;
        U1 = __builtin_elementwise_fma((v2){A1.y, A1.y}, W1, U1);
        U1 = __builtin_elementwise_fma((v2){A1.z, A1.z}, W2, U1);
        U1 = __builtin_elementwise_fma((v2){A1.w, A1.w}, W3, U1);
        U2 = (v2){A2.x, A2.x} * W0;
        U2 = __builtin_elementwise_fma((v2){A2.y, A2.y}, W1, U2);
        U2 = __builtin_elementwise_fma((v2){A2.z, A2.z}, W2, U2);
        U2 = __builtin_elementwise_fma((v2){A2.w, A2.w}, W3, U2);
        U3 = (v2){A3.x, A3.x} * W0;
        U3 = __builtin_elementwise_fma((v2){A3.y, A3.y}, W1, U3);
        U3 = __builtin_elementwise_fma((v2){A3.z, A3.z}, W2, U3);
        U3 = __builtin_elementwise_fma((v2){A3.w, A3.w}, W3, U3);
    };

    // logit partial -> softmax weight p (verified cross-lane set: shfl/DPP/swz)
    auto site_p = [&](v2 U0, v2 U1, v2 U2, v2 U3) -> float {
        v2 ds = U0 * cv0;
        ds = __builtin_elementwise_fma(U1, cv1, ds);
        ds = __builtin_elementwise_fma(U2, cv2, ds);
        ds = __builtin_elementwise_fma(U3, cv3, ds);
        float part = ds.x + ds.y;
        float lg   = part + __shfl_xor(part, 32, 64);  // + other half's terms
        float e1   = __builtin_exp2f(lg);
        float s = e1;
        s = DPP_ADDF(s, 0xB1);    // xor1  (quad_perm [1,0,3,2])
        s = DPP_ADDF(s, 0x4E);    // xor2  (quad_perm [2,3,0,1])
        s = DPP_ADDF(s, 0x141);   // xor4  (row_half_mirror)
        s = DPP_ADDF(s, 0x140);   // xor8  (row_mirror)
        s += __builtin_bit_cast(float,
              __builtin_amdgcn_ds_swizzle(__builtin_bit_cast(int, s), 0x401F)); // xor16
        return e1 * __builtin_amdgcn_rcpf(s);
    };

    // stream A walks sites (n=0..15)x(kl=0..8); stream B = A + 16 capsules
    const float* wp = w3 + l64 * 4;          // advances 512 floats/site
    // B offsets: +16*16384 floats in input, +16*9*512 = 73728 floats in w3

    for (int n = 0; n < 16; ++n) {
#pragma unroll
        for (int kl = 0; kl < 9; ++kl) {
            const float* apA = ipb + n * 16384 + (kl / 3) * 512 + (kl % 3) * 16;
            const float* apB = apA + 262144;

            const float4 aA0 = *(const float4*)(apA + 0);
            const float4 aA1 = *(const float4*)(apA + 4);
            const float4 aA2 = *(const float4*)(apA + 8);
            const float4 aA3 = *(const float4*)(apA + 12);
            const float4 aB0 = *(const float4*)(apB + 0);
            const float4 aB1 = *(const float4*)(apB + 4);
            const float4 aB2 = *(const float4*)(apB + 8);
            const float4 aB3 = *(const float4*)(apB + 12);

            const float4 qA0 = *(const float4*)(wp);
            const float4 qA1 = *(const float4*)(wp + 256);
            const float4 qB0 = *(const float4*)(wp + 73728);
            const float4 qB1 = *(const float4*)(wp + 73728 + 256);

            v2 uA0, uA1, uA2, uA3, uB0, uB1, uB2, uB3;
            site_u(aA0, aA1, aA2, aA3, qA0, qA1, uA0, uA1, uA2, uA3);
            site_u(aB0, aB1, aB2, aB3, qB0, qB1, uB0, uB1, uB2, uB3);

            const float pA = site_p(uA0, uA1, uA2, uA3);
            const float pB = site_p(uB0, uB1, uB2, uB3);

            const v2 pA2 = {pA, pA};
            const v2 pB2 = {pB, pB};
            acA0 = __builtin_elementwise_fma(pA2, uA0, acA0);
            acA1 = __builtin_elementwise_fma(pA2, uA1, acA1);
            acA2 = __builtin_elementwise_fma(pA2, uA2, acA2);
            acA3 = __builtin_elementwise_fma(pA2, uA3, acA3);
            acB0 = __builtin_elementwise_fma(pB2, uB0, acB0);
            acB1 = __builtin_elementwise_fma(pB2, uB1, acB1);
            acB2 = __builtin_elementwise_fma(pB2, uB2, acB2);
            acB3 = __builtin_elementwise_fma(pB2, uB3, acB3);

            wp += 512;
        }
    }

    // merge streams
    v2 acc0 = acA0 + acB0;
    v2 acc1 = acA1 + acB1;
    v2 acc2 = acA2 + acB2;
    v2 acc3 = acA3 + acB3;

    // ---- fused LayerNorm: 8 local + cross-half exchange (shfl_xor 32) ----
    v2 s2 = (acc0 + acc1) + (acc2 + acc3);
    float s8  = s2.x + s2.y;
    float s16 = s8 + __shfl_xor(s8, 32, 64);
    float mu  = s16 * 0.0625f;
    v2 mv = {mu, mu};

    v2 vv = {0.f, 0.f};
    v2 t0 = acc0 - mv; vv = __builtin_elementwise_fma(t0, t0, vv);
    v2 t1 = acc1 - mv; vv = __builtin_elementwise_fma(t1, t1, vv);
    v2 t2 = acc2 - mv; vv = __builtin_elementwise_fma(t2, t2, vv);
    v2 t3 = acc3 - mv; vv = __builtin_elementwise_fma(t3, t3, vv);
    float v8  = vv.x + vv.y;
    float v16 = v8 + __shfl_xor(v8, 32, 64);
    float rstd = __builtin_amdgcn_rsqf(v16 * 0.0625f + 1e-5f);
    v2 rs2 = {rstd, rstd};

    const int db = 2 * half;
    float* op = out + (((size_t)b * 32 + m) * (HOUT * WOUT) + hw) * 16 + db;
    {
        v2 g  = *(const v2*)(gamma + 0 + db);
        v2 be = *(const v2*)(beta  + 0 + db);
        *(v2*)(op + 0)  = __builtin_elementwise_fma(t0 * rs2, g, be);
    }
    {
        v2 g  = *(const v2*)(gamma + 4 + db);
        v2 be = *(const v2*)(beta  + 4 + db);
        *(v2*)(op + 4)  = __builtin_elementwise_fma(t1 * rs2, g, be);
    }
    {
        v2 g  = *(const v2*)(gamma + 8 + db);
        v2 be = *(const v2*)(beta  + 8 + db);
        *(v2*)(op + 8)  = __builtin_elementwise_fma(t2 * rs2, g, be);
    }
    {
        v2 g  = *(const v2*)(gamma + 12 + db);
        v2 be = *(const v2*)(beta  + 12 + db);
        *(v2*)(op + 12) = __builtin_elementwise_fma(t3 * rs2, g, be);
    }
}

extern "C" void kernel_launch(void* const* d_in, const int* in_sizes, int n_in,
                              void* d_out, int out_size, void* d_ws, size_t ws_size,
                              hipStream_t stream) {
    const float* input = (const float*)d_in[0];
    const float* ncv   = (const float*)d_in[1];
    const float* wt    = (const float*)d_in[2];
    const float* gamma = (const float*)d_in[3];
    const float* beta  = (const float*)d_in[4];
    float* out = (float*)d_out;
    float* w3  = (float*)d_ws;                 // 576 KB

    prep_w<<<dim3(576), dim3(256), 0, stream>>>(wt, w3);
    caps_all<<<dim3(1800), dim3(256), 0, stream>>>(input, ncv, w3, gamma, beta, out);
}

// Round 11
// 341.570 us; speedup vs baseline: 1.4962x; 1.4962x over previous
//
#include <hip/hip_runtime.h>

#define HOUT 15
#define WOUT 15
// input  (32, 32, 32, 32, 16)  fp32
// ncv    (32, 32, 15, 15, 16)  fp32
// w      (3, 3, 32, 4, 4, 32)  fp32
// out    (32, 32, 15, 15, 16)  fp32

typedef float v2 __attribute__((ext_vector_type(2)));

// DPP butterfly add step (ctrl must be a literal). Compiler-generated DPP
// gets hazard NOPs inserted automatically — verified correct rounds 1-4, 8, 9.
#define DPP_ADDF(x, ctrl) \
    ((x) + __builtin_bit_cast(float, __builtin_amdgcn_update_dpp( \
        0, __builtin_bit_cast(int, (x)), (ctrl), 0xF, 0xF, true)))

// ---- explicit VOP3P packed fp32 ops (full-rate on CDNA) -------------------
// Plain packed: d = a*b (+ c), both elements.
__device__ __forceinline__ v2 pk_mul(v2 a, v2 b) {
    v2 d;
    asm("v_pk_mul_f32 %0, %1, %2" : "=v"(d) : "v"(a), "v"(b));
    return d;
}
__device__ __forceinline__ v2 pk_fma(v2 a, v2 b, v2 c) {
    v2 d;
    asm("v_pk_fma_f32 %0, %1, %2, %3" : "=v"(d) : "v"(a), "v"(b), "v"(c));
    return d;
}
// Broadcast forms: src0 is an SGPR PAIR (s_load result used directly as the
// instruction's one scalar operand — no splat movs). op_sel/op_sel_hi pick
// which element of the pair feeds the lo/hi result:
//   lo-broadcast: op_sel[0]=0, op_sel_hi[0]=0
//   hi-broadcast: op_sel[0]=1, op_sel_hi[0]=1
__device__ __forceinline__ v2 pk_mul_s_lo(v2 s, v2 w) {
    v2 d;
    asm("v_pk_mul_f32 %0, %1, %2 op_sel:[0,0] op_sel_hi:[0,1]"
        : "=v"(d) : "s"(s), "v"(w));
    return d;
}
__device__ __forceinline__ v2 pk_fma_s_lo(v2 s, v2 w, v2 c) {
    v2 d;
    asm("v_pk_fma_f32 %0, %1, %2, %3 op_sel:[0,0,0] op_sel_hi:[0,1,1]"
        : "=v"(d) : "s"(s), "v"(w), "v"(c));
    return d;
}
__device__ __forceinline__ v2 pk_fma_s_hi(v2 s, v2 w, v2 c) {
    v2 d;
    asm("v_pk_fma_f32 %0, %1, %2, %3 op_sel:[1,0,0] op_sel_hi:[1,1,1]"
        : "=v"(d) : "s"(s), "v"(w), "v"(c));
    return d;
}

// ---------------- pass 0: repack w for the (m, d-half) lane mapping --------
// w[kl][n][x][d][m] -> w3[n][kl][xq][l64][e]  (147456 floats = 576 KB)
// lane l64 = m + 32*half owns d in {2*half, 2*half+1}. Element e of quad xq:
//   x = 2*xq + (e>>1), d = 2*half + (e&1)
__global__ __launch_bounds__(256) void prep_w(const float* __restrict__ wt,
                                              float* __restrict__ w3)
{
    const int t   = blockIdx.x * 256 + threadIdx.x;   // 0..147455
    const int e   = t & 3;
    const int l64 = (t >> 2) & 63;
    const int xq  = (t >> 8) & 1;
    const int r   = t >> 9;          // n*9 + kl
    const int kl  = r % 9;
    const int n   = r / 9;
    const int mm  = l64 & 31;
    const int hf  = l64 >> 5;
    const int x   = 2 * xq + (e >> 1);
    const int d   = 2 * hf + (e & 1);
    w3[t] = wt[((kl * 32 + n) * 16 + x * 4 + d) * 32 + mm];
}

// ---------------- fused kernel: one wave per output position ---------------
// Structure = round 9 (best verified: dual streams, SMEM av, shfl/DPP/swizzle
// softmax, fused LN). Change vs R9: the u/dot/acc MAC bulk is explicit
// v_pk_fma_f32/v_pk_mul_f32 with op_sel broadcasts reading av straight from
// the SGPR pair — guarantees packed math and eliminates splat movs.
// (R10's VMEM-av launder regressed 273->466 us; reverted.)
// NOTE: no min-waves clause (round 2: forced cap -> spill -> 3.4x regression).
__global__ __launch_bounds__(256) void caps_all(
    const float* __restrict__ input,
    const float* __restrict__ ncv,
    const float* __restrict__ w3,
    const float* __restrict__ gamma,
    const float* __restrict__ beta,
    float* __restrict__ out)
{
    const int tid  = threadIdx.x;
    const int l64  = tid & 63;
    const int m    = l64 & 31;
    const int half = l64 >> 5;

    // wave-uniform position -> SGPRs, so av loads are s_load
    const int posu = __builtin_amdgcn_readfirstlane(blockIdx.x * 4 + (tid >> 6));
    const int b  = posu / (HOUT * WOUT);
    const int hw = posu % (HOUT * WOUT);
    const int h  = hw / WOUT;
    const int wo = hw % WOUT;

    // input[b][n][h][w][16]: strides 524288 / 16384 / 512 / 16
    const float* ipb = input + (size_t)b * 524288 + (h * 2) * 512 + (wo * 2) * 16;

    // cv = ncv[b][m][h][wo][a*4 + 2*half + {0,1}], pre-scaled by 0.25*log2e
    const float* cvp = ncv + (((size_t)b * 32 + m) * (HOUT * WOUT) + hw) * 16 + 2 * half;
    const float SC = 0.36067376022224085f;   // 0.25 * log2(e)
    v2 sc2 = {SC, SC};
    v2 cv0 = *(const v2*)(cvp +  0) * sc2;
    v2 cv1 = *(const v2*)(cvp +  4) * sc2;
    v2 cv2 = *(const v2*)(cvp +  8) * sc2;
    v2 cv3 = *(const v2*)(cvp + 12) * sc2;

    v2 acA0 = {0.f,0.f}, acA1 = {0.f,0.f}, acA2 = {0.f,0.f}, acA3 = {0.f,0.f};
    v2 acB0 = {0.f,0.f}, acB1 = {0.f,0.f}, acB2 = {0.f,0.f}, acB3 = {0.f,0.f};

    // u[a] for one site from av pairs (SGPR) and w quads (VGPR).
    // ap: av[a, x0..1] at ap[2a], av[a, x2..3] at ap[2a+1] (v2 units)
    auto site_u = [&](v2 p0, v2 p1, v2 p2_, v2 p3, v2 p4, v2 p5, v2 p6, v2 p7,
                      const float4& Q0, const float4& Q1,
                      v2& U0, v2& U1, v2& U2, v2& U3) {
        const v2 W0 = {Q0.x, Q0.y}, W1 = {Q0.z, Q0.w};
        const v2 W2 = {Q1.x, Q1.y}, W3 = {Q1.z, Q1.w};
        U0 = pk_mul_s_lo(p0, W0);            // av[0,0]*W0
        U0 = pk_fma_s_hi(p0, W1, U0);        // + av[0,1]*W1
        U0 = pk_fma_s_lo(p1, W2, U0);        // + av[0,2]*W2
        U0 = pk_fma_s_hi(p1, W3, U0);        // + av[0,3]*W3
        U1 = pk_mul_s_lo(p2_, W0);
        U1 = pk_fma_s_hi(p2_, W1, U1);
        U1 = pk_fma_s_lo(p3, W2, U1);
        U1 = pk_fma_s_hi(p3, W3, U1);
        U2 = pk_mul_s_lo(p4, W0);
        U2 = pk_fma_s_hi(p4, W1, U2);
        U2 = pk_fma_s_lo(p5, W2, U2);
        U2 = pk_fma_s_hi(p5, W3, U2);
        U3 = pk_mul_s_lo(p6, W0);
        U3 = pk_fma_s_hi(p6, W1, U3);
        U3 = pk_fma_s_lo(p7, W2, U3);
        U3 = pk_fma_s_hi(p7, W3, U3);
    };

    // logit partial -> softmax weight p (verified cross-lane set)
    auto site_p = [&](v2 U0, v2 U1, v2 U2, v2 U3) -> float {
        v2 ds = pk_mul(U0, cv0);
        ds = pk_fma(U1, cv1, ds);
        ds = pk_fma(U2, cv2, ds);
        ds = pk_fma(U3, cv3, ds);
        float part = ds.x + ds.y;
        float lg   = part + __shfl_xor(part, 32, 64);  // + other half's terms
        float e1   = __builtin_exp2f(lg);
        float s = e1;
        s = DPP_ADDF(s, 0xB1);    // xor1  (quad_perm [1,0,3,2])
        s = DPP_ADDF(s, 0x4E);    // xor2  (quad_perm [2,3,0,1])
        s = DPP_ADDF(s, 0x141);   // xor4  (row_half_mirror)
        s = DPP_ADDF(s, 0x140);   // xor8  (row_mirror)
        s += __builtin_bit_cast(float,
              __builtin_amdgcn_ds_swizzle(__builtin_bit_cast(int, s), 0x401F)); // xor16
        return e1 * __builtin_amdgcn_rcpf(s);
    };

    // stream A walks sites (n=0..15)x(kl=0..8); stream B = A + 16 capsules
    const float* wp = w3 + l64 * 4;          // advances 512 floats/site
    // B offsets: +262144 floats in input, +73728 floats in w3

    for (int n = 0; n < 16; ++n) {
#pragma unroll
        for (int kl = 0; kl < 9; ++kl) {
            const float* apA = ipb + n * 16384 + (kl / 3) * 512 + (kl % 3) * 16;
            const float* apB = apA + 262144;

            // av pairs (uniform address -> s_load, stay in SGPR pairs)
            const v2 aA0 = *(const v2*)(apA + 0),  aA1 = *(const v2*)(apA + 2);
            const v2 aA2 = *(const v2*)(apA + 4),  aA3 = *(const v2*)(apA + 6);
            const v2 aA4 = *(const v2*)(apA + 8),  aA5 = *(const v2*)(apA + 10);
            const v2 aA6 = *(const v2*)(apA + 12), aA7 = *(const v2*)(apA + 14);
            const v2 aB0 = *(const v2*)(apB + 0),  aB1 = *(const v2*)(apB + 2);
            const v2 aB2 = *(const v2*)(apB + 4),  aB3 = *(const v2*)(apB + 6);
            const v2 aB4 = *(const v2*)(apB + 8),  aB5 = *(const v2*)(apB + 10);
            const v2 aB6 = *(const v2*)(apB + 12), aB7 = *(const v2*)(apB + 14);

            const float4 qA0 = *(const float4*)(wp);
            const float4 qA1 = *(const float4*)(wp + 256);
            const float4 qB0 = *(const float4*)(wp + 73728);
            const float4 qB1 = *(const float4*)(wp + 73728 + 256);

            v2 uA0, uA1, uA2, uA3, uB0, uB1, uB2, uB3;
            site_u(aA0, aA1, aA2, aA3, aA4, aA5, aA6, aA7,
                   qA0, qA1, uA0, uA1, uA2, uA3);
            site_u(aB0, aB1, aB2, aB3, aB4, aB5, aB6, aB7,
                   qB0, qB1, uB0, uB1, uB2, uB3);

            const float pA = site_p(uA0, uA1, uA2, uA3);
            const float pB = site_p(uB0, uB1, uB2, uB3);

            const v2 pA2 = {pA, pA};
            const v2 pB2 = {pB, pB};
            acA0 = pk_fma(pA2, uA0, acA0);
            acA1 = pk_fma(pA2, uA1, acA1);
            acA2 = pk_fma(pA2, uA2, acA2);
            acA3 = pk_fma(pA2, uA3, acA3);
            acB0 = pk_fma(pB2, uB0, acB0);
            acB1 = pk_fma(pB2, uB1, acB1);
            acB2 = pk_fma(pB2, uB2, acB2);
            acB3 = pk_fma(pB2, uB3, acB3);

            wp += 512;
        }
    }

    // merge streams
    v2 acc0 = acA0 + acB0;
    v2 acc1 = acA1 + acB1;
    v2 acc2 = acA2 + acB2;
    v2 acc3 = acA3 + acB3;

    // ---- fused LayerNorm: 8 local + cross-half exchange (shfl_xor 32) ----
    v2 s2 = (acc0 + acc1) + (acc2 + acc3);
    float s8  = s2.x + s2.y;
    float s16 = s8 + __shfl_xor(s8, 32, 64);
    float mu  = s16 * 0.0625f;
    v2 mv = {mu, mu};

    v2 vv = {0.f, 0.f};
    v2 t0 = acc0 - mv; vv = __builtin_elementwise_fma(t0, t0, vv);
    v2 t1 = acc1 - mv; vv = __builtin_elementwise_fma(t1, t1, vv);
    v2 t2 = acc2 - mv; vv = __builtin_elementwise_fma(t2, t2, vv);
    v2 t3 = acc3 - mv; vv = __builtin_elementwise_fma(t3, t3, vv);
    float v8  = vv.x + vv.y;
    float v16 = v8 + __shfl_xor(v8, 32, 64);
    float rstd = __builtin_amdgcn_rsqf(v16 * 0.0625f + 1e-5f);
    v2 rs2 = {rstd, rstd};

    const int db = 2 * half;
    float* op = out + (((size_t)b * 32 + m) * (HOUT * WOUT) + hw) * 16 + db;
    {
        v2 g  = *(const v2*)(gamma + 0 + db);
        v2 be = *(const v2*)(beta  + 0 + db);
        *(v2*)(op + 0)  = __builtin_elementwise_fma(t0 * rs2, g, be);
    }
    {
        v2 g  = *(const v2*)(gamma + 4 + db);
        v2 be = *(const v2*)(beta  + 4 + db);
        *(v2*)(op + 4)  = __builtin_elementwise_fma(t1 * rs2, g, be);
    }
    {
        v2 g  = *(const v2*)(gamma + 8 + db);
        v2 be = *(const v2*)(beta  + 8 + db);
        *(v2*)(op + 8)  = __builtin_elementwise_fma(t2 * rs2, g, be);
    }
    {
        v2 g  = *(const v2*)(gamma + 12 + db);
        v2 be = *(const v2*)(beta  + 12 + db);
        *(v2*)(op + 12) = __builtin_elementwise_fma(t3 * rs2, g, be);
    }
}

extern "C" void kernel_launch(void* const* d_in, const int* in_sizes, int n_in,
                              void* d_out, int out_size, void* d_ws, size_t ws_size,
                              hipStream_t stream) {
    const float* input = (const float*)d_in[0];
    const float* ncv   = (const float*)d_in[1];
    const float* wt    = (const float*)d_in[2];
    const float* gamma = (const float*)d_in[3];
    const float* beta  = (const float*)d_in[4];
    float* out = (float*)d_out;
    float* w3  = (float*)d_ws;                 // 576 KB

    prep_w<<<dim3(576), dim3(256), 0, stream>>>(wt, w3);
    caps_all<<<dim3(1800), dim3(256), 0, stream>>>(input, ncv, w3, gamma, beta, out);
}